// Round 1
// baseline (720.849 us; speedup 1.0000x reference)
//
#include <hip/hip_runtime.h>

#define LDIM 50
#define MBIN 262144
#define ODIM 155
#define VOCABSZ 100

// workspace layout (floats)
#define WS_T  0        // 6*100*50 = 30000 : T[s][v][d], s=0 pe-slot (b_pred folded), s=1..5 ve-slots
#define WS_TB 30000    // 100*50 : oe[v] @ W_bin[50:100] + b_bin
#define WS_LG 35000    // 300 : attention logits  [0..99]=pe, [100..199]=ve, [200..299]=oe

// ---------------------------------------------------------------------------
// Precompute vocab-indexed tables (trivial cost, ~2 MFLOP)
// ---------------------------------------------------------------------------
__global__ __launch_bounds__(64) void precompute_kernel(
    const float* __restrict__ pe, const float* __restrict__ ve, const float* __restrict__ oe,
    const float* __restrict__ W_pred, const float* __restrict__ b_pred,
    const float* __restrict__ W_bin, const float* __restrict__ b_bin,
    const float* __restrict__ W_att, const float* __restrict__ b_att,
    float* __restrict__ ws)
{
    const int bid = blockIdx.x;
    const int t = threadIdx.x;
    if (bid < 600) {
        const int s = bid / VOCABSZ, v = bid % VOCABSZ;
        if (t < LDIM) {
            const float* E = (s == 0) ? pe : ve;
            float acc = (s == 0) ? b_pred[t] : 0.0f;
            for (int e = 0; e < LDIM; ++e)
                acc += E[v*LDIM + e] * W_pred[(s*LDIM + e)*LDIM + t];
            ws[WS_T + (s*VOCABSZ + v)*LDIM + t] = acc;
        }
    } else if (bid < 700) {
        const int v = bid - 600;
        if (t < LDIM) {
            float acc = b_bin[t];
            for (int e = 0; e < LDIM; ++e)
                acc += oe[v*LDIM + e] * W_bin[(LDIM + e)*LDIM + t];
            ws[WS_TB + v*LDIM + t] = acc;
        }
    } else {
        const int g = (bid - 700)*64 + t;
        if (g < 300) {
            const int which = g / VOCABSZ, v = g % VOCABSZ;
            const float* E = (which == 0) ? pe : ((which == 1) ? ve : oe);
            float acc = b_att[0];
            for (int e = 0; e < LDIM; ++e)
                acc += E[v*LDIM + e] * W_att[e];
            ws[WS_LG + g] = acc;
        }
    }
}

// ---------------------------------------------------------------------------
// Build one predicate node's h_pred into hout[], return exp(h·W_att + b_att)
// (unnormalized softmax weight for stage 2; logits are small, no max-sub needed)
// ---------------------------------------------------------------------------
__device__ __forceinline__ float build_pred_node(
    int n, const int* __restrict__ pred_ids, const int* __restrict__ var_ids,
    const float* __restrict__ pe, const float* __restrict__ ve,
    const float* __restrict__ T, const float* __restrict__ lg,
    const float* __restrict__ W_att, float batt, float* __restrict__ hout)
{
    const int p = pred_ids[n];
    int v[5];
#pragma unroll
    for (int s = 0; s < 5; ++s) v[s] = var_ids[n*5 + s];

    // stage-1 attention softmax: logits are precomputed per-vocab
    const float e0 = __expf(lg[p]);
    float ek[5];
    float den = e0;
#pragma unroll
    for (int s = 0; s < 5; ++s) { ek[s] = __expf(lg[VOCABSZ + v[s]]); den += ek[s]; }
    const float inv = 1.0f / den;

    float lin[LDIM], num[LDIM];
    {   // lin = T0[p] (b_pred folded in)
        const float2* r = reinterpret_cast<const float2*>(T + p*LDIM);
#pragma unroll
        for (int i = 0; i < LDIM/2; ++i) { float2 t2 = r[i]; lin[2*i] = t2.x; lin[2*i+1] = t2.y; }
    }
#pragma unroll
    for (int s = 0; s < 5; ++s) {
        const float2* r = reinterpret_cast<const float2*>(T + ((s+1)*VOCABSZ + v[s])*LDIM);
#pragma unroll
        for (int i = 0; i < LDIM/2; ++i) { float2 t2 = r[i]; lin[2*i] += t2.x; lin[2*i+1] += t2.y; }
    }
    {   // num = e0 * pe[p]
        const float2* r = reinterpret_cast<const float2*>(pe + p*LDIM);
#pragma unroll
        for (int i = 0; i < LDIM/2; ++i) { float2 t2 = r[i]; num[2*i] = e0*t2.x; num[2*i+1] = e0*t2.y; }
    }
#pragma unroll
    for (int s = 0; s < 5; ++s) {
        const float2* r = reinterpret_cast<const float2*>(ve + v[s]*LDIM);
#pragma unroll
        for (int i = 0; i < LDIM/2; ++i) { float2 t2 = r[i]; num[2*i] += ek[s]*t2.x; num[2*i+1] += ek[s]*t2.y; }
    }

    float l = batt;
#pragma unroll
    for (int d = 0; d < LDIM; ++d) {
        float hv = fmaxf(lin[d], 0.0f) + num[d]*inv;
        hout[d] = hv;
        l += hv * W_att[d];
    }
    return __expf(l);
}

// ---------------------------------------------------------------------------
// Fused main kernel: one thread per binary node, full chain to output row.
// Private LDS slot (stride 51 -> conflict-free) holds whichever h vector
// needs runtime-index access; accumulators live in unrolled VGPR arrays.
// ---------------------------------------------------------------------------
__global__ __launch_bounds__(64) void fused_kernel(
    const float* __restrict__ pe, const float* __restrict__ ve, const float* __restrict__ oe,
    const float* __restrict__ W_bin,
    const float* __restrict__ W_un, const float* __restrict__ b_un,
    const float* __restrict__ W_univ, const float* __restrict__ b_univ,
    const float* __restrict__ W_att, const float* __restrict__ b_att,
    const float* __restrict__ W_fin, const float* __restrict__ b_fin,
    const int* __restrict__ pred_ids, const int* __restrict__ var_ids,
    const int* __restrict__ op_ids,
    const float* __restrict__ ws, float* __restrict__ out)
{
    __shared__ float hs[64 * 51];
    float* slot = hs + threadIdx.x * 51;
    const int j = blockIdx.x * 64 + threadIdx.x;

    const float* T  = ws + WS_T;
    const float* Tb = ws + WS_TB;
    const float* lg = ws + WS_LG;
    const float batt = b_att[0];

    // ---- predicate node A = 2j -> slot ----
    float w0 = build_pred_node(2*j, pred_ids, var_ids, pe, ve, T, lg, W_att, batt, slot);

    const int op = op_ids[j];
    const float w1 = __expf(lg[2*VOCABSZ + op]);

    // lin2 = Tb[op] (b_bin folded) + h0 @ W_bin[0:50]
    float lin2[LDIM];
    {
        const float2* r = reinterpret_cast<const float2*>(Tb + op*LDIM);
#pragma unroll
        for (int i = 0; i < LDIM/2; ++i) { float2 t2 = r[i]; lin2[2*i] = t2.x; lin2[2*i+1] = t2.y; }
    }
    for (int e = 0; e < LDIM; ++e) {
        const float he = slot[e];
        const float* wr = W_bin + e*LDIM;  // uniform address -> scalar loads
#pragma unroll
        for (int d = 0; d < LDIM; ++d) lin2[d] += he * wr[d];
    }

    // num2 = w0*h0 + w1*oe[op]
    float num2[LDIM];
    {
        const float2* r = reinterpret_cast<const float2*>(oe + op*LDIM);
#pragma unroll
        for (int i = 0; i < LDIM/2; ++i) { float2 t2 = r[i]; num2[2*i] = w1*t2.x; num2[2*i+1] = w1*t2.y; }
    }
#pragma unroll
    for (int d = 0; d < LDIM; ++d) num2[d] += w0 * slot[d];

    // stash lin2 into slot (h0 fully consumed) to cap register pressure
#pragma unroll
    for (int d = 0; d < LDIM; ++d) slot[d] = lin2[d];

    // ---- predicate node B = 2j+1 -> registers ----
    float hB[LDIM];
    const float w2 = build_pred_node(2*j+1, pred_ids, var_ids, pe, ve, T, lg, W_att, batt, hB);
    const float inv2 = 1.0f / (w0 + w1 + w2);
#pragma unroll
    for (int d = 0; d < LDIM; ++d) num2[d] += w2 * hB[d];

    // swap: lin2 <- slot (stash), slot <- hB
#pragma unroll
    for (int d = 0; d < LDIM; ++d) { float t = slot[d]; slot[d] = hB[d]; lin2[d] = t; }

    // lin2 += h1 @ W_bin[100:150]
    for (int e = 0; e < LDIM; ++e) {
        const float he = slot[e];
        const float* wr = W_bin + (2*LDIM + e)*LDIM;
#pragma unroll
        for (int d = 0; d < LDIM; ++d) lin2[d] += he * wr[d];
    }

    // h_bin -> slot
#pragma unroll
    for (int d = 0; d < LDIM; ++d) slot[d] = fmaxf(lin2[d], 0.0f) + num2[d]*inv2;

    // ---- h_un = relu(h_bin @ W_un + b_un) -> slot ----
    {
        float acc[LDIM];
#pragma unroll
        for (int d = 0; d < LDIM; ++d) acc[d] = b_un[d];
        for (int e = 0; e < LDIM; ++e) {
            const float he = slot[e];
            const float* wr = W_un + e*LDIM;
#pragma unroll
            for (int d = 0; d < LDIM; ++d) acc[d] += he * wr[d];
        }
#pragma unroll
        for (int d = 0; d < LDIM; ++d) slot[d] = fmaxf(acc[d], 0.0f);
    }

    // ---- h_q = relu(h_un @ W_univ + b_univ) -> slot ----
    {
        float acc[LDIM];
#pragma unroll
        for (int d = 0; d < LDIM; ++d) acc[d] = b_univ[d];
        for (int e = 0; e < LDIM; ++e) {
            const float he = slot[e];
            const float* wr = W_univ + e*LDIM;
#pragma unroll
            for (int d = 0; d < LDIM; ++d) acc[d] += he * wr[d];
        }
#pragma unroll
        for (int d = 0; d < LDIM; ++d) slot[d] = fmaxf(acc[d], 0.0f);
    }

    // ---- out[j] = h_q @ W_fin + b_fin, in 5 chunks of 31 outputs ----
    float* orow = out + (size_t)j * ODIM;
    for (int c = 0; c < 5; ++c) {
        float acc[31];
        const int obase = c * 31;
#pragma unroll
        for (int o = 0; o < 31; ++o) acc[o] = b_fin[obase + o];
        for (int d = 0; d < LDIM; ++d) {
            const float hq = slot[d];
            const float* wr = W_fin + d*ODIM + obase;
#pragma unroll
            for (int o = 0; o < 31; ++o) acc[o] += hq * wr[o];
        }
#pragma unroll
        for (int o = 0; o < 31; ++o) orow[obase + o] = acc[o];
    }
}

// ---------------------------------------------------------------------------
extern "C" void kernel_launch(void* const* d_in, const int* in_sizes, int n_in,
                              void* d_out, int out_size, void* d_ws, size_t ws_size,
                              hipStream_t stream) {
    const float* pe     = (const float*)d_in[0];
    const float* ve     = (const float*)d_in[1];
    const float* oe     = (const float*)d_in[2];
    const float* W_pred = (const float*)d_in[3];
    const float* b_pred = (const float*)d_in[4];
    const float* W_bin  = (const float*)d_in[5];
    const float* b_bin  = (const float*)d_in[6];
    const float* W_un   = (const float*)d_in[7];
    const float* b_un   = (const float*)d_in[8];
    const float* W_univ = (const float*)d_in[9];
    const float* b_univ = (const float*)d_in[10];
    const float* W_att  = (const float*)d_in[11];
    const float* b_att  = (const float*)d_in[12];
    const float* W_fin  = (const float*)d_in[13];
    const float* b_fin  = (const float*)d_in[14];
    const int* pred_ids = (const int*)d_in[15];
    const int* var_ids  = (const int*)d_in[16];
    const int* op_ids   = (const int*)d_in[17];
    float* out = (float*)d_out;
    float* ws  = (float*)d_ws;

    precompute_kernel<<<705, 64, 0, stream>>>(pe, ve, oe, W_pred, b_pred,
                                              W_bin, b_bin, W_att, b_att, ws);
    fused_kernel<<<MBIN/64, 64, 0, stream>>>(pe, ve, oe, W_bin, W_un, b_un,
                                             W_univ, b_univ, W_att, b_att,
                                             W_fin, b_fin, pred_ids, var_ids,
                                             op_ids, ws, out);
}